// Round 2
// baseline (20213.533 us; speedup 1.0000x reference)
//
#include <hip/hip_runtime.h>

#define Bb 256
#define Ll 256
#define Dd 512
#define Hh 8
#define NLAYER 6
#define FFd 2048
#define BL 65536          // total rows = B*L
#define GB 64             // batches per attention group
#define NGRP 4            // BL batch groups
#define FCH 16384         // rows per FFN chunk
#define NFCH 4

using bf16x8 = __attribute__((ext_vector_type(8))) short;
using f32x4  = __attribute__((ext_vector_type(4))) float;

__device__ __forceinline__ float bf2f(unsigned short u) {
  return __uint_as_float(((unsigned)u) << 16);
}
__device__ __forceinline__ unsigned short f2bf(float f) {
  unsigned u = __float_as_uint(f);
  u += 0x7fffu + ((u >> 16) & 1u);
  return (unsigned short)(u >> 16);
}

// ---------------- weight convert: fp32 [K][N] -> bf16 [N][K] (per layer) -------------
__global__ __launch_bounds__(256) void wconv_kernel(
    const float* __restrict__ src, unsigned short* __restrict__ dst,
    int kshift, int N, long dstLayerStride, long srcLayerStride)
{
  int l = blockIdx.y;
  int K = 1 << kshift;
  long total = (long)K * N;
  const float* s = src + (long)l * srcLayerStride;
  unsigned short* dd = dst + (long)l * dstLayerStride;
  for (long i = (long)blockIdx.x * blockDim.x + threadIdx.x; i < total;
       i += (long)gridDim.x * blockDim.x) {
    long n = i >> kshift;
    long k = i & (K - 1);
    dd[i] = f2bf(s[k * N + n]);
  }
}

__global__ __launch_bounds__(256) void bconcat_kernel(
    const float* __restrict__ bq, const float* __restrict__ bk,
    const float* __restrict__ bv, float* __restrict__ bqkv)
{
  int i = blockIdx.x * 256 + threadIdx.x;
  if (i >= NLAYER * 1536) return;
  int l = i / 1536, n = i % 1536;
  float v;
  if (n < 512)       v = bq[l * 512 + n];
  else if (n < 1024) v = bk[l * 512 + n - 512];
  else               v = bv[l * 512 + n - 1024];
  bqkv[i] = v;
}

// ---------------- embedding (h rows in [l,b] order: row = l*256 + b) -----------------
__global__ __launch_bounds__(128) void embed_kernel(
    const int* __restrict__ x, const float* __restrict__ emb,
    const float* __restrict__ rate1, float* __restrict__ h)
{
  int rowid = blockIdx.x;              // = l*Bb + b  (x is [L][B] so x[rowid])
  int tok = x[rowid];
  float r1 = rate1[0];
  int d = threadIdx.x * 4;
  float4 e = *(const float4*)(emb + (long)tok * Dd + d);
  float4 o = make_float4(r1 * e.x, r1 * e.y, r1 * e.z, r1 * e.w);
  *(float4*)(h + (long)rowid * Dd + d) = o;
}

__global__ __launch_bounds__(128) void scatter_kernel(
    const int* __restrict__ x, const float* __restrict__ coord,
    const int* __restrict__ atok, const int* __restrict__ aidx,
    const int* __restrict__ bidx, const float* __restrict__ emb,
    const float* __restrict__ cw, const float* __restrict__ cb,
    const float* __restrict__ rate1, const float* __restrict__ rate2,
    float* __restrict__ h)
{
  int i = blockIdx.x;
  int bi = bidx[i], ai = aidx[i], tk = atok[i];
  int l = ai + 1;
  float c0 = coord[i * 3], c1 = coord[i * 3 + 1], c2 = coord[i * 3 + 2];
  float r1 = rate1[0], r2 = rate2[0];
  int d = threadIdx.x * 4;
  float4 e  = *(const float4*)(emb + (long)tk * Dd + d);
  float4 w0 = *(const float4*)(cw + d);
  float4 w1 = *(const float4*)(cw + 512 + d);
  float4 w2 = *(const float4*)(cw + 1024 + d);
  float4 bb = *(const float4*)(cb + d);
  float4 pos;
  pos.x = e.x + c0 * w0.x + c1 * w1.x + c2 * w2.x + bb.x;
  pos.y = e.y + c0 * w0.y + c1 * w1.y + c2 * w2.y + bb.y;
  pos.z = e.z + c0 * w0.z + c1 * w1.z + c2 * w2.z + bb.z;
  pos.w = e.w + c0 * w0.w + c1 * w1.w + c2 * w2.w + bb.w;
  int rowid = l * Bb + bi;             // [l,b] order
  int tokx = x[rowid];
  float4 ex = *(const float4*)(emb + (long)tokx * Dd + d);
  float4 o;
  o.x = r1 * ex.x + r2 * pos.x;
  o.y = r1 * ex.y + r2 * pos.y;
  o.z = r1 * ex.z + r2 * pos.z;
  o.w = r1 * ex.w + r2 * pos.w;
  *(float4*)(h + (long)rowid * Dd + d) = o;
}

// ---------------- LayerNorm (wave per row) -------------------------------------------
// FINAL==0: write bf16 [rows][512] to outb. FINAL==1: write fp32 IN PLACE to outf.
template<int FINAL>
__global__ __launch_bounds__(256) void ln_kernel(
    const float* __restrict__ in, const float* __restrict__ g,
    const float* __restrict__ be, unsigned short* __restrict__ outb,
    float* __restrict__ outf)
{
  int gw = blockIdx.x * 4 + (threadIdx.x >> 6);
  int lane = threadIdx.x & 63;
  const float4* row = (const float4*)(in + (long)gw * Dd);
  float4 a = row[lane * 2];
  float4 c = row[lane * 2 + 1];
  float sum = a.x + a.y + a.z + a.w + c.x + c.y + c.z + c.w;
  float sq  = a.x*a.x + a.y*a.y + a.z*a.z + a.w*a.w
            + c.x*c.x + c.y*c.y + c.z*c.z + c.w*c.w;
  #pragma unroll
  for (int off = 32; off; off >>= 1) {
    sum += __shfl_xor(sum, off);
    sq  += __shfl_xor(sq, off);
  }
  float mean = sum * (1.f / 512.f);
  float var  = sq * (1.f / 512.f) - mean * mean;
  float rstd = rsqrtf(var + 1e-6f);
  int d = lane * 8;
  float4 g0 = *(const float4*)(g + d),  g1 = *(const float4*)(g + d + 4);
  float4 b0 = *(const float4*)(be + d), b1 = *(const float4*)(be + d + 4);
  float xv[8] = {a.x, a.y, a.z, a.w, c.x, c.y, c.z, c.w};
  float gv[8] = {g0.x, g0.y, g0.z, g0.w, g1.x, g1.y, g1.z, g1.w};
  float bv[8] = {b0.x, b0.y, b0.z, b0.w, b1.x, b1.y, b1.z, b1.w};
  float o[8];
  #pragma unroll
  for (int i = 0; i < 8; i++) o[i] = (xv[i] - mean) * rstd * gv[i] + bv[i];
  if (FINAL == 0) {
    int4 pk;
    pk.x = (int)f2bf(o[0]) | ((int)f2bf(o[1]) << 16);
    pk.y = (int)f2bf(o[2]) | ((int)f2bf(o[3]) << 16);
    pk.z = (int)f2bf(o[4]) | ((int)f2bf(o[5]) << 16);
    pk.w = (int)f2bf(o[6]) | ((int)f2bf(o[7]) << 16);
    *(int4*)(outb + (long)gw * Dd + d) = pk;
  } else {
    float* o2 = outf + (long)gw * Dd + d;   // in place (h already [L,B,D])
    *(float4*)o2       = make_float4(o[0], o[1], o[2], o[3]);
    *(float4*)(o2 + 4) = make_float4(o[4], o[5], o[6], o[7]);
  }
}

// ---------------- GEMM: C[M,N] = A[M,K](bf16) x Bt[N,K](bf16) ------------------------
// MODE 0: Out = bf16(C + bias);  MODE 1: Out = bf16(relu(C + bias));
// MODE 2: Hacc += C + bias (fp32 residual accumulate)
template<int MODE>
__global__ __launch_bounds__(256) void gemm_kernel(
    const unsigned short* __restrict__ A, const unsigned short* __restrict__ Bt,
    const float* __restrict__ bias, unsigned short* __restrict__ Out,
    float* __restrict__ Hacc, int N, int K)
{
  __shared__ unsigned short As[128 * 40];
  __shared__ unsigned short Bs[128 * 40];
  const int tid = threadIdx.x;
  const int wave = tid >> 6, lane = tid & 63;
  const int quad = lane >> 4, c16 = lane & 15;
  const int m0 = blockIdx.x * 128, n0 = blockIdx.y * 128;
  const int wm = (wave >> 1) << 6, wn = (wave & 1) << 6;

  f32x4 acc[4][4] = {};

  const int srow = tid & 127;
  const bool isB = tid >= 128;
  const unsigned short* gsrc =
      isB ? (Bt + (long)(n0 + srow) * K) : (A + (long)(m0 + srow) * K);
  unsigned short* lds = (isB ? Bs : As) + srow * 40;

  for (int k0 = 0; k0 < K; k0 += 32) {
    int4 v0 = *(const int4*)(gsrc + k0);
    int4 v1 = *(const int4*)(gsrc + k0 + 8);
    int4 v2 = *(const int4*)(gsrc + k0 + 16);
    int4 v3 = *(const int4*)(gsrc + k0 + 24);
    __syncthreads();
    *(int4*)(lds)      = v0;
    *(int4*)(lds + 8)  = v1;
    *(int4*)(lds + 16) = v2;
    *(int4*)(lds + 24) = v3;
    __syncthreads();
    bf16x8 af[4], bfr[4];
    #pragma unroll
    for (int t = 0; t < 4; t++) {
      af[t]  = *(const bf16x8*)(As + (wm + t * 16 + c16) * 40 + quad * 8);
      bfr[t] = *(const bf16x8*)(Bs + (wn + t * 16 + c16) * 40 + quad * 8);
    }
    #pragma unroll
    for (int i = 0; i < 4; i++)
      #pragma unroll
      for (int j = 0; j < 4; j++)
        acc[i][j] = __builtin_amdgcn_mfma_f32_16x16x32_bf16(af[i], bfr[j], acc[i][j], 0, 0, 0);
  }

  #pragma unroll
  for (int i = 0; i < 4; i++) {
    #pragma unroll
    for (int j = 0; j < 4; j++) {
      int row = m0 + wm + i * 16 + quad * 4;
      int col = n0 + wn + j * 16 + c16;
      float bvv = bias[col];
      #pragma unroll
      for (int r = 0; r < 4; r++) {
        float v = acc[i][j][r] + bvv;
        if (MODE == 1) v = fmaxf(v, 0.f);
        if (MODE <= 1) Out[(long)(row + r) * N + col] = f2bf(v);
        else           Hacc[(long)(row + r) * N + col] += v;
      }
    }
  }
}

// ---- QKV GEMM with remapped rows: tile row r -> A row l*256+(b0+brel), out row brel*256+l
__global__ __launch_bounds__(256) void gemm_qkv_kernel(
    const unsigned short* __restrict__ A, const unsigned short* __restrict__ Bt,
    const float* __restrict__ bias, unsigned short* __restrict__ Out, int b0)
{
  const int N = 1536, K = 512;
  __shared__ unsigned short As[128 * 40];
  __shared__ unsigned short Bs[128 * 40];
  const int tid = threadIdx.x;
  const int wave = tid >> 6, lane = tid & 63;
  const int quad = lane >> 4, c16 = lane & 15;
  const int m0 = blockIdx.x * 128, n0 = blockIdx.y * 128;
  const int wm = (wave >> 1) << 6, wn = (wave & 1) << 6;

  f32x4 acc[4][4] = {};

  const int srow = tid & 127;
  const bool isB = tid >= 128;
  int r = m0 + srow;
  long arow = (long)(r >> 6) * 256 + b0 + (r & 63);   // l*256 + b
  const unsigned short* gsrc =
      isB ? (Bt + (long)(n0 + srow) * K) : (A + arow * K);
  unsigned short* lds = (isB ? Bs : As) + srow * 40;

  for (int k0 = 0; k0 < K; k0 += 32) {
    int4 v0 = *(const int4*)(gsrc + k0);
    int4 v1 = *(const int4*)(gsrc + k0 + 8);
    int4 v2 = *(const int4*)(gsrc + k0 + 16);
    int4 v3 = *(const int4*)(gsrc + k0 + 24);
    __syncthreads();
    *(int4*)(lds)      = v0;
    *(int4*)(lds + 8)  = v1;
    *(int4*)(lds + 16) = v2;
    *(int4*)(lds + 24) = v3;
    __syncthreads();
    bf16x8 af[4], bfr[4];
    #pragma unroll
    for (int t = 0; t < 4; t++) {
      af[t]  = *(const bf16x8*)(As + (wm + t * 16 + c16) * 40 + quad * 8);
      bfr[t] = *(const bf16x8*)(Bs + (wn + t * 16 + c16) * 40 + quad * 8);
    }
    #pragma unroll
    for (int i = 0; i < 4; i++)
      #pragma unroll
      for (int j = 0; j < 4; j++)
        acc[i][j] = __builtin_amdgcn_mfma_f32_16x16x32_bf16(af[i], bfr[j], acc[i][j], 0, 0, 0);
  }

  #pragma unroll
  for (int i = 0; i < 4; i++) {
    #pragma unroll
    for (int j = 0; j < 4; j++) {
      int col = n0 + wn + j * 16 + c16;
      float bvv = bias[col];
      #pragma unroll
      for (int rr = 0; rr < 4; rr++) {
        int row = m0 + wm + i * 16 + quad * 4 + rr;   // chunk-local r
        int orow = (row & 63) * 256 + (row >> 6);     // brel*256 + l
        Out[(long)orow * N + col] = f2bf(acc[i][j][rr] + bvv);
      }
    }
  }
}

// ---------------- attention: one block per (brel, head); QKV chunk is [b,l] order ----
__global__ __launch_bounds__(256) void attn_kernel(
    const unsigned short* __restrict__ qkv, const int* __restrict__ x,
    unsigned short* __restrict__ ctx, int b0)
{
  __shared__ unsigned short Ks[256 * 66];
  __shared__ float qs[4][64];
  __shared__ float ps[4][256];
  __shared__ int msk[256];
  const int bh = blockIdx.x;
  const int brel = bh >> 3, hh = bh & 7;
  const int b = b0 + brel;
  const int tid = threadIdx.x, wave = tid >> 6, lane = tid & 63;

  msk[tid] = (x[tid * Bb + b] == 0);
  const int lrow = tid >> 6;
  for (int r0 = 0; r0 < 256; r0 += 4) {
    int rr = r0 + lrow;
    long base = ((long)(brel * 256 + rr)) * 1536 + hh * 64 + lane;
    Ks[rr * 66 + lane] = qkv[base + 512];
  }
  __syncthreads();

  const unsigned short* Vg = qkv + (long)(brel * 256) * 1536 + 1024 + hh * 64 + lane;
  const float scale = 0.125f;

  for (int l = wave; l < 256; l += 4) {
    long qbase = ((long)(brel * 256 + l)) * 1536 + hh * 64;
    qs[wave][lane] = bf2f(qkv[qbase + lane]);
    float s0 = 0.f, s1 = 0.f, s2 = 0.f, s3 = 0.f;
    #pragma unroll 8
    for (int d = 0; d < 64; d += 2) {
      float q0 = qs[wave][d], q1 = qs[wave][d + 1];
      unsigned k0 = *(const unsigned*)(Ks + lane * 66 + d);
      unsigned k1 = *(const unsigned*)(Ks + (64 + lane) * 66 + d);
      unsigned k2 = *(const unsigned*)(Ks + (128 + lane) * 66 + d);
      unsigned k3 = *(const unsigned*)(Ks + (192 + lane) * 66 + d);
      s0 = fmaf(q0, __uint_as_float(k0 << 16), fmaf(q1, __uint_as_float(k0 & 0xffff0000u), s0));
      s1 = fmaf(q0, __uint_as_float(k1 << 16), fmaf(q1, __uint_as_float(k1 & 0xffff0000u), s1));
      s2 = fmaf(q0, __uint_as_float(k2 << 16), fmaf(q1, __uint_as_float(k2 & 0xffff0000u), s2));
      s3 = fmaf(q0, __uint_as_float(k3 << 16), fmaf(q1, __uint_as_float(k3 & 0xffff0000u), s3));
    }
    s0 = msk[lane]       ? -1e9f : s0 * scale;
    s1 = msk[64 + lane]  ? -1e9f : s1 * scale;
    s2 = msk[128 + lane] ? -1e9f : s2 * scale;
    s3 = msk[192 + lane] ? -1e9f : s3 * scale;
    float mx = fmaxf(fmaxf(s0, s1), fmaxf(s2, s3));
    #pragma unroll
    for (int off = 32; off; off >>= 1) mx = fmaxf(mx, __shfl_xor(mx, off));
    float e0 = __expf(s0 - mx), e1 = __expf(s1 - mx);
    float e2 = __expf(s2 - mx), e3 = __expf(s3 - mx);
    float sm = e0 + e1 + e2 + e3;
    #pragma unroll
    for (int off = 32; off; off >>= 1) sm += __shfl_xor(sm, off);
    float inv = 1.f / sm;
    ps[wave][lane]       = e0 * inv;
    ps[wave][64 + lane]  = e1 * inv;
    ps[wave][128 + lane] = e2 * inv;
    ps[wave][192 + lane] = e3 * inv;
    float acc = 0.f;
    #pragma unroll 4
    for (int k = 0; k < 256; k += 4) {
      float4 p = *(const float4*)&ps[wave][k];
      acc = fmaf(p.x, bf2f(Vg[(k + 0) * 1536]), acc);
      acc = fmaf(p.y, bf2f(Vg[(k + 1) * 1536]), acc);
      acc = fmaf(p.z, bf2f(Vg[(k + 2) * 1536]), acc);
      acc = fmaf(p.w, bf2f(Vg[(k + 3) * 1536]), acc);
    }
    // ctx row in [l,b] order
    ctx[((long)(l * Bb + b)) * 512 + hh * 64 + lane] = f2bf(acc);
  }
}

// ---------------- launch -------------------------------------------------------------
extern "C" void kernel_launch(void* const* d_in, const int* in_sizes, int n_in,
                              void* d_out, int out_size, void* d_ws, size_t ws_size,
                              hipStream_t stream) {
  const int*   x       = (const int*)d_in[0];
  const float* acoord  = (const float*)d_in[1];
  const int*   atok    = (const int*)d_in[2];
  const int*   aidx    = (const int*)d_in[3];
  const int*   bidx    = (const int*)d_in[4];
  const float* emb     = (const float*)d_in[5];
  const float* coord_w = (const float*)d_in[6];
  const float* coord_b = (const float*)d_in[7];
  const float* rate1   = (const float*)d_in[8];
  const float* rate2   = (const float*)d_in[9];
  const float* ln1_g   = (const float*)d_in[10];
  const float* ln1_b   = (const float*)d_in[11];
  const float* wq      = (const float*)d_in[12];
  const float* bq      = (const float*)d_in[13];
  const float* wk      = (const float*)d_in[14];
  const float* bk      = (const float*)d_in[15];
  const float* wv      = (const float*)d_in[16];
  const float* bv      = (const float*)d_in[17];
  const float* wo      = (const float*)d_in[18];
  const float* bo      = (const float*)d_in[19];
  const float* ln2_g   = (const float*)d_in[20];
  const float* ln2_b   = (const float*)d_in[21];
  const float* w1      = (const float*)d_in[22];
  const float* b1      = (const float*)d_in[23];
  const float* w2      = (const float*)d_in[24];
  const float* b2      = (const float*)d_in[25];
  const float* lnf_g   = (const float*)d_in[26];
  const float* lnf_b   = (const float*)d_in[27];
  float* out = (float*)d_out;

  // h (residual stream, fp32, [L,B,D] row order) lives in d_out itself.
  float* h = out;

  // ws layout (total 172,003,328 bytes):
  char* ws = (char*)d_ws;
  unsigned short* wqkvT = (unsigned short*)(ws);                  //  9,437,184
  unsigned short* woT   = (unsigned short*)(ws + 9437184UL);      //  3,145,728
  unsigned short* w1T   = (unsigned short*)(ws + 12582912UL);     // 12,582,912
  unsigned short* w2T   = (unsigned short*)(ws + 25165824UL);     // 12,582,912
  float*          bqkv  = (float*)(ws + 37748736UL);              //     36,864
  unsigned short* bufC  = (unsigned short*)(ws + 37785600UL);     // 67,108,864 (LN out / ctx)
  unsigned short* region= (unsigned short*)(ws + 104894464UL);    // 67,108,864 (QKV chunk / FFN mid)

  dim3 wgrid(256, NLAYER);
  wconv_kernel<<<wgrid, 256, 0, stream>>>(wq, wqkvT,           9, 512,  786432L,  262144L);
  wconv_kernel<<<wgrid, 256, 0, stream>>>(wk, wqkvT + 262144,  9, 512,  786432L,  262144L);
  wconv_kernel<<<wgrid, 256, 0, stream>>>(wv, wqkvT + 524288,  9, 512,  786432L,  262144L);
  wconv_kernel<<<wgrid, 256, 0, stream>>>(wo, woT,             9, 512,  262144L,  262144L);
  wconv_kernel<<<wgrid, 256, 0, stream>>>(w1, w1T,             9, 2048, 1048576L, 1048576L);
  wconv_kernel<<<wgrid, 256, 0, stream>>>(w2, w2T,            11, 512,  1048576L, 1048576L);
  bconcat_kernel<<<36, 256, 0, stream>>>(bq, bk, bv, bqkv);

  embed_kernel<<<BL, 128, 0, stream>>>(x, emb, rate1, h);
  scatter_kernel<<<Bb * 128, 128, 0, stream>>>(x, acoord, atok, aidx, bidx, emb,
                                               coord_w, coord_b, rate1, rate2, h);

  for (int l = 0; l < NLAYER; l++) {
    ln_kernel<0><<<16384, 256, 0, stream>>>(h, ln1_g + l * 512, ln1_b + l * 512, bufC, nullptr);
    for (int g = 0; g < NGRP; g++) {
      gemm_qkv_kernel<<<dim3(128, 12), 256, 0, stream>>>(
          bufC, wqkvT + (long)l * 786432, bqkv + l * 1536, region, g * GB);
      attn_kernel<<<GB * Hh, 256, 0, stream>>>(region, x, bufC, g * GB);
    }
    gemm_kernel<2><<<dim3(512, 4), 256, 0, stream>>>(
        bufC, woT + (long)l * 262144, bo + l * 512, nullptr, h, 512, 512);
    ln_kernel<0><<<16384, 256, 0, stream>>>(h, ln2_g + l * 512, ln2_b + l * 512, bufC, nullptr);
    for (int c = 0; c < NFCH; c++) {
      gemm_kernel<1><<<dim3(128, 16), 256, 0, stream>>>(
          bufC + (long)c * FCH * 512, w1T + (long)l * 1048576, b1 + l * 2048,
          region, nullptr, 2048, 512);
      gemm_kernel<2><<<dim3(128, 4), 256, 0, stream>>>(
          region, w2T + (long)l * 1048576, b2 + l * 512,
          nullptr, h + (long)c * FCH * 512, 512, 2048);
    }
  }
  ln_kernel<1><<<16384, 256, 0, stream>>>(h, lnf_g, lnf_b, nullptr, h);
}

// Round 4
// 6159.530 us; speedup vs baseline: 3.2817x; 3.2817x over previous
//
#include <hip/hip_runtime.h>

#define Bb 256
#define Ll 256
#define Dd 512
#define Hh 8
#define NLAYER 6
#define FFd 2048
#define BL 65536          // total rows = B*L
#define GB 64             // batches per attention group
#define NGRP 4            // batch groups
#define FCH 16384         // rows per FFN chunk
#define NFCH 4

using bf16x8 = __attribute__((ext_vector_type(8))) short;
using f32x4  = __attribute__((ext_vector_type(4))) float;

__device__ __forceinline__ float bf2f(unsigned short u) {
  return __uint_as_float(((unsigned)u) << 16);
}
__device__ __forceinline__ unsigned short f2bf(float f) {
  unsigned u = __float_as_uint(f);
  u += 0x7fffu + ((u >> 16) & 1u);
  return (unsigned short)(u >> 16);
}

// async global->LDS, 16B per lane; LDS dest = wave-uniform base + lane*16 (HW-defined)
__device__ __forceinline__ void async16(const unsigned short* g, unsigned short* l) {
  __builtin_amdgcn_global_load_lds(
      (const __attribute__((address_space(1))) void*)g,
      (__attribute__((address_space(3))) void*)l, 16, 0, 0);
}

// ---------------- weight convert: fp32 [K][N] -> bf16 [N][K] (per layer) -------------
__global__ __launch_bounds__(256) void wconv_kernel(
    const float* __restrict__ src, unsigned short* __restrict__ dst,
    int kshift, int N, long dstLayerStride, long srcLayerStride)
{
  int l = blockIdx.y;
  int K = 1 << kshift;
  long total = (long)K * N;
  const float* s = src + (long)l * srcLayerStride;
  unsigned short* dd = dst + (long)l * dstLayerStride;
  for (long i = (long)blockIdx.x * blockDim.x + threadIdx.x; i < total;
       i += (long)gridDim.x * blockDim.x) {
    long n = i >> kshift;
    long k = i & (K - 1);
    dd[i] = f2bf(s[k * N + n]);
  }
}

__global__ __launch_bounds__(256) void bconcat_kernel(
    const float* __restrict__ bq, const float* __restrict__ bk,
    const float* __restrict__ bv, float* __restrict__ bqkv)
{
  int i = blockIdx.x * 256 + threadIdx.x;
  if (i >= NLAYER * 1536) return;
  int l = i / 1536, n = i % 1536;
  float v;
  if (n < 512)       v = bq[l * 512 + n];
  else if (n < 1024) v = bk[l * 512 + n - 512];
  else               v = bv[l * 512 + n - 1024];
  bqkv[i] = v;
}

// ---------------- embedding (h rows in [l,b] order: row = l*256 + b) -----------------
__global__ __launch_bounds__(128) void embed_kernel(
    const int* __restrict__ x, const float* __restrict__ emb,
    const float* __restrict__ rate1, float* __restrict__ h)
{
  int rowid = blockIdx.x;              // = l*Bb + b  (x is [L][B] so x[rowid])
  int tok = x[rowid];
  float r1 = rate1[0];
  int d = threadIdx.x * 4;
  float4 e = *(const float4*)(emb + (long)tok * Dd + d);
  float4 o = make_float4(r1 * e.x, r1 * e.y, r1 * e.z, r1 * e.w);
  *(float4*)(h + (long)rowid * Dd + d) = o;
}

__global__ __launch_bounds__(128) void scatter_kernel(
    const int* __restrict__ x, const float* __restrict__ coord,
    const int* __restrict__ atok, const int* __restrict__ aidx,
    const int* __restrict__ bidx, const float* __restrict__ emb,
    const float* __restrict__ cw, const float* __restrict__ cb,
    const float* __restrict__ rate1, const float* __restrict__ rate2,
    float* __restrict__ h)
{
  int i = blockIdx.x;
  int bi = bidx[i], ai = aidx[i], tk = atok[i];
  int l = ai + 1;
  float c0 = coord[i * 3], c1 = coord[i * 3 + 1], c2 = coord[i * 3 + 2];
  float r1 = rate1[0], r2 = rate2[0];
  int d = threadIdx.x * 4;
  float4 e  = *(const float4*)(emb + (long)tk * Dd + d);
  float4 w0 = *(const float4*)(cw + d);
  float4 w1 = *(const float4*)(cw + 512 + d);
  float4 w2 = *(const float4*)(cw + 1024 + d);
  float4 bb = *(const float4*)(cb + d);
  float4 pos;
  pos.x = e.x + c0 * w0.x + c1 * w1.x + c2 * w2.x + bb.x;
  pos.y = e.y + c0 * w0.y + c1 * w1.y + c2 * w2.y + bb.y;
  pos.z = e.z + c0 * w0.z + c1 * w1.z + c2 * w2.z + bb.z;
  pos.w = e.w + c0 * w0.w + c1 * w1.w + c2 * w2.w + bb.w;
  int rowid = l * Bb + bi;             // [l,b] order
  int tokx = x[rowid];
  float4 ex = *(const float4*)(emb + (long)tokx * Dd + d);
  float4 o;
  o.x = r1 * ex.x + r2 * pos.x;
  o.y = r1 * ex.y + r2 * pos.y;
  o.z = r1 * ex.z + r2 * pos.z;
  o.w = r1 * ex.w + r2 * pos.w;
  *(float4*)(h + (long)rowid * Dd + d) = o;
}

// ---------------- LayerNorm (wave per row) -------------------------------------------
template<int FINAL>
__global__ __launch_bounds__(256) void ln_kernel(
    const float* __restrict__ in, const float* __restrict__ g,
    const float* __restrict__ be, unsigned short* __restrict__ outb,
    float* __restrict__ outf)
{
  int gw = blockIdx.x * 4 + (threadIdx.x >> 6);
  int lane = threadIdx.x & 63;
  const float4* row = (const float4*)(in + (long)gw * Dd);
  float4 a = row[lane * 2];
  float4 c = row[lane * 2 + 1];
  float sum = a.x + a.y + a.z + a.w + c.x + c.y + c.z + c.w;
  float sq  = a.x*a.x + a.y*a.y + a.z*a.z + a.w*a.w
            + c.x*c.x + c.y*c.y + c.z*c.z + c.w*c.w;
  #pragma unroll
  for (int off = 32; off; off >>= 1) {
    sum += __shfl_xor(sum, off);
    sq  += __shfl_xor(sq, off);
  }
  float mean = sum * (1.f / 512.f);
  float var  = sq * (1.f / 512.f) - mean * mean;
  float rstd = rsqrtf(var + 1e-6f);
  int d = lane * 8;
  float4 g0 = *(const float4*)(g + d),  g1 = *(const float4*)(g + d + 4);
  float4 b0 = *(const float4*)(be + d), b1 = *(const float4*)(be + d + 4);
  float xv[8] = {a.x, a.y, a.z, a.w, c.x, c.y, c.z, c.w};
  float gv[8] = {g0.x, g0.y, g0.z, g0.w, g1.x, g1.y, g1.z, g1.w};
  float bv[8] = {b0.x, b0.y, b0.z, b0.w, b1.x, b1.y, b1.z, b1.w};
  float o[8];
  #pragma unroll
  for (int i = 0; i < 8; i++) o[i] = (xv[i] - mean) * rstd * gv[i] + bv[i];
  if (FINAL == 0) {
    int4 pk;
    pk.x = (int)f2bf(o[0]) | ((int)f2bf(o[1]) << 16);
    pk.y = (int)f2bf(o[2]) | ((int)f2bf(o[3]) << 16);
    pk.z = (int)f2bf(o[4]) | ((int)f2bf(o[5]) << 16);
    pk.w = (int)f2bf(o[6]) | ((int)f2bf(o[7]) << 16);
    *(int4*)(outb + (long)gw * Dd + d) = pk;
  } else {
    float* o2 = outf + (long)gw * Dd + d;
    *(float4*)o2       = make_float4(o[0], o[1], o[2], o[3]);
    *(float4*)(o2 + 4) = make_float4(o[4], o[5], o[6], o[7]);
  }
}

// ---------------- GEMM: C[M,N] = A[M,K](bf16) x Bt[N,K](bf16) ------------------------
// m97-style: BK=64, async global_load_lds staging, XOR-swizzled LDS (no padding).
// MODE 0: Out = bf16(C+bias); 1: Out = bf16(relu(C+bias)); 2: Hacc += C+bias.
// REMAP 1: A row r -> (r>>6)*256 + b0 + (r&63); out row -> (r&63)*256 + (r>>6).
template<int MODE, int REMAP>
__global__ __launch_bounds__(256, 2) void gemm_kernel(
    const unsigned short* __restrict__ A, const unsigned short* __restrict__ Bt,
    const float* __restrict__ bias, unsigned short* __restrict__ Out,
    float* __restrict__ Hacc, int N, int K, int b0)
{
  __shared__ unsigned short As[128 * 64];
  __shared__ unsigned short Bs[128 * 64];
  const int tid = threadIdx.x;
  const int wave = tid >> 6, lane = tid & 63;
  const int quad = lane >> 4, c16 = lane & 15;
  const int m0 = blockIdx.x * 128, n0 = blockIdx.y * 128;
  const int wm = (wave >> 1) << 6, wn = (wave & 1) << 6;

  f32x4 acc[4][4] = {};

  // swizzle: lane loads global k-chunk (lane&7)^(lane>>3) of row lane>>3;
  // lands at physical chunk lane&7 -> physical chunk c of row r holds logical c^r
  const int kch = (((lane & 7) ^ (lane >> 3)) << 3);
  const int rsub = lane >> 3;

  for (int k0 = 0; k0 < K; k0 += 64) {
    __syncthreads();
    #pragma unroll
    for (int t = 0; t < 4; t++) {
      int row = wave * 32 + t * 8 + rsub;         // tile-local row 0..127
      long ar;
      int r = m0 + row;
      if (REMAP) ar = (long)(r >> 6) * 256 + b0 + (r & 63);
      else       ar = r;
      async16(A  + ar * (long)K + k0 + kch, As + (wave * 32 + t * 8) * 64);
      async16(Bt + (long)(n0 + row) * K + k0 + kch, Bs + (wave * 32 + t * 8) * 64);
    }
    __syncthreads();

    bf16x8 af[4][2], bfr[4][2];
    #pragma unroll
    for (int tt = 0; tt < 4; tt++) {
      int ma = wm + tt * 16 + c16;
      int nb = wn + tt * 16 + c16;
      #pragma unroll
      for (int s = 0; s < 2; s++) {
        af[tt][s]  = *(const bf16x8*)(As + ma * 64 + ((((s << 2) | quad) ^ (ma & 7)) << 3));
        bfr[tt][s] = *(const bf16x8*)(Bs + nb * 64 + ((((s << 2) | quad) ^ (nb & 7)) << 3));
      }
    }
    #pragma unroll
    for (int s = 0; s < 2; s++)
      #pragma unroll
      for (int i = 0; i < 4; i++)
        #pragma unroll
        for (int j = 0; j < 4; j++)
          acc[i][j] = __builtin_amdgcn_mfma_f32_16x16x32_bf16(af[i][s], bfr[j][s], acc[i][j], 0, 0, 0);
  }

  #pragma unroll
  for (int i = 0; i < 4; i++) {
    #pragma unroll
    for (int j = 0; j < 4; j++) {
      int col = n0 + wn + j * 16 + c16;
      float bvv = bias[col];
      #pragma unroll
      for (int r = 0; r < 4; r++) {
        int row = m0 + wm + i * 16 + quad * 4 + r;
        float v = acc[i][j][r] + bvv;
        if (MODE == 1) v = fmaxf(v, 0.f);
        if (MODE <= 1) {
          long orow = REMAP ? (long)((row & 63) * 256 + (row >> 6)) : (long)row;
          Out[orow * N + col] = f2bf(v);
        } else {
          Hacc[(long)row * N + col] += v;
        }
      }
    }
  }
}

// ---------------- attention: MFMA flash, one block per (brel, head) ------------------
// QKV chunk is [b,l] row order; 4 waves x 64 Q rows; K/V tiles of 64 keys.
__global__ __launch_bounds__(256) void attn_kernel(
    const unsigned short* __restrict__ qkv, const int* __restrict__ x,
    unsigned short* __restrict__ ctx, int b0)
{
  __shared__ unsigned short Kt[64 * 72];       // K[kr][d]
  __shared__ unsigned short Vt[64 * 72];       // V^T[d][kr]
  __shared__ unsigned short Pt[4][64 * 72];    // per-wave P[m][kr]
  __shared__ int msk[256];
  const int bh = blockIdx.x;
  const int brel = bh >> 3, hh = bh & 7;
  const int b = b0 + brel;
  const int tid = threadIdx.x, wave = tid >> 6, lane = tid & 63;
  const int quad = lane >> 4, c16 = lane & 15;

  msk[tid] = (x[tid * Bb + b] == 0);

  // preload Q A-frags: rows l = wave*64 + mt*16 + c16, k(d) = s*32 + quad*8
  bf16x8 aq[4][2];
  const long rbase = (long)(brel * 256);
  #pragma unroll
  for (int mt = 0; mt < 4; mt++) {
    int l = wave * 64 + mt * 16 + c16;
    const unsigned short* qp = qkv + (rbase + l) * 1536 + hh * 64 + quad * 8;
    aq[mt][0] = *(const bf16x8*)(qp);
    aq[mt][1] = *(const bf16x8*)(qp + 32);
  }

  f32x4 Oacc[4][4] = {};   // [mtile][dtile]
  f32x4 mrun[4], lrun[4];
  #pragma unroll
  for (int mt = 0; mt < 4; mt++) {
    mrun[mt] = (f32x4){-1e30f, -1e30f, -1e30f, -1e30f};
    lrun[mt] = (f32x4){0.f, 0.f, 0.f, 0.f};
  }

  for (int kt = 0; kt < 4; kt++) {
    __syncthreads();
    {
      // 16 shorts per thread = TWO int4 (int4 = 8 shorts!)
      int krl = tid >> 2, ch = tid & 3;
      const unsigned short* kp = qkv + (rbase + kt * 64 + krl) * 1536 + 512 + hh * 64 + ch * 16;
      *(int4*)(Kt + krl * 72 + ch * 16)     = *(const int4*)kp;
      *(int4*)(Kt + krl * 72 + ch * 16 + 8) = *(const int4*)(kp + 8);
      const unsigned short* vp = qkv + (rbase + kt * 64 + krl) * 1536 + 1024 + hh * 64 + ch * 16;
      int4 v0 = *(const int4*)vp;
      int4 v1 = *(const int4*)(vp + 8);
      const unsigned short* a0 = (const unsigned short*)&v0;
      const unsigned short* a1 = (const unsigned short*)&v1;
      #pragma unroll
      for (int t = 0; t < 8; t++)
        Vt[(ch * 16 + t) * 72 + krl] = a0[t];
      #pragma unroll
      for (int t = 0; t < 8; t++)
        Vt[(ch * 16 + 8 + t) * 72 + krl] = a1[t];
    }
    __syncthreads();

    // S tile = Q(64) x K_tile(64)^T
    f32x4 sa[4][4] = {};
    bf16x8 bk_[4][2];
    #pragma unroll
    for (int nt = 0; nt < 4; nt++) {
      bk_[nt][0] = *(const bf16x8*)(Kt + (nt * 16 + c16) * 72 + quad * 8);
      bk_[nt][1] = *(const bf16x8*)(Kt + (nt * 16 + c16) * 72 + 32 + quad * 8);
    }
    #pragma unroll
    for (int mt = 0; mt < 4; mt++)
      #pragma unroll
      for (int nt = 0; nt < 4; nt++) {
        sa[mt][nt] = __builtin_amdgcn_mfma_f32_16x16x32_bf16(aq[mt][0], bk_[nt][0], sa[mt][nt], 0, 0, 0);
        sa[mt][nt] = __builtin_amdgcn_mfma_f32_16x16x32_bf16(aq[mt][1], bk_[nt][1], sa[mt][nt], 0, 0, 0);
      }

    int mq[4];
    #pragma unroll
    for (int nt = 0; nt < 4; nt++) mq[nt] = msk[kt * 64 + nt * 16 + c16];

    #pragma unroll
    for (int mt = 0; mt < 4; mt++) {
      #pragma unroll
      for (int nt = 0; nt < 4; nt++)
        #pragma unroll
        for (int r = 0; r < 4; r++) {
          float v = sa[mt][nt][r] * 0.125f;
          sa[mt][nt][r] = mq[nt] ? -1e9f : v;
        }
      f32x4 mx = sa[mt][0];
      #pragma unroll
      for (int nt = 1; nt < 4; nt++)
        #pragma unroll
        for (int r = 0; r < 4; r++) mx[r] = fmaxf(mx[r], sa[mt][nt][r]);
      #pragma unroll
      for (int off = 1; off < 16; off <<= 1)
        #pragma unroll
        for (int r = 0; r < 4; r++) mx[r] = fmaxf(mx[r], __shfl_xor(mx[r], off));
      f32x4 mnew, alpha;
      #pragma unroll
      for (int r = 0; r < 4; r++) {
        mnew[r]  = fmaxf(mrun[mt][r], mx[r]);
        alpha[r] = __expf(mrun[mt][r] - mnew[r]);
      }
      mrun[mt] = mnew;
      f32x4 rsum = (f32x4){0.f, 0.f, 0.f, 0.f};
      #pragma unroll
      for (int nt = 0; nt < 4; nt++)
        #pragma unroll
        for (int r = 0; r < 4; r++) {
          float p = __expf(sa[mt][nt][r] - mnew[r]);
          sa[mt][nt][r] = p;
          rsum[r] += p;
        }
      #pragma unroll
      for (int off = 1; off < 16; off <<= 1)
        #pragma unroll
        for (int r = 0; r < 4; r++) rsum[r] += __shfl_xor(rsum[r], off);
      #pragma unroll
      for (int r = 0; r < 4; r++) lrun[mt][r] = lrun[mt][r] * alpha[r] + rsum[r];
      #pragma unroll
      for (int dt = 0; dt < 4; dt++)
        #pragma unroll
        for (int r = 0; r < 4; r++) Oacc[mt][dt][r] *= alpha[r];
      unsigned short* pw = Pt[wave] + (mt * 16 + quad * 4) * 72 + c16;
      #pragma unroll
      for (int nt = 0; nt < 4; nt++)
        #pragma unroll
        for (int r = 0; r < 4; r++) pw[r * 72 + nt * 16] = f2bf(sa[mt][nt][r]);
    }

    // O += P x V   (A = P rows, B = V^T rows)
    bf16x8 bv_[4][2], ap[4][2];
    #pragma unroll
    for (int dt = 0; dt < 4; dt++) {
      bv_[dt][0] = *(const bf16x8*)(Vt + (dt * 16 + c16) * 72 + quad * 8);
      bv_[dt][1] = *(const bf16x8*)(Vt + (dt * 16 + c16) * 72 + 32 + quad * 8);
    }
    #pragma unroll
    for (int mt = 0; mt < 4; mt++) {
      ap[mt][0] = *(const bf16x8*)(Pt[wave] + (mt * 16 + c16) * 72 + quad * 8);
      ap[mt][1] = *(const bf16x8*)(Pt[wave] + (mt * 16 + c16) * 72 + 32 + quad * 8);
    }
    #pragma unroll
    for (int mt = 0; mt < 4; mt++)
      #pragma unroll
      for (int dt = 0; dt < 4; dt++) {
        Oacc[mt][dt] = __builtin_amdgcn_mfma_f32_16x16x32_bf16(ap[mt][0], bv_[dt][0], Oacc[mt][dt], 0, 0, 0);
        Oacc[mt][dt] = __builtin_amdgcn_mfma_f32_16x16x32_bf16(ap[mt][1], bv_[dt][1], Oacc[mt][dt], 0, 0, 0);
      }
  }

  // normalize + write ctx ([l,b] row order)
  #pragma unroll
  for (int mt = 0; mt < 4; mt++)
    #pragma unroll
    for (int r = 0; r < 4; r++) {
      int lq = wave * 64 + mt * 16 + quad * 4 + r;
      float inv = 1.f / lrun[mt][r];
      long orow = (long)lq * Bb + b;
      #pragma unroll
      for (int dt = 0; dt < 4; dt++)
        ctx[orow * 512 + hh * 64 + dt * 16 + c16] = f2bf(Oacc[mt][dt][r] * inv);
    }
}

// ---------------- launch -------------------------------------------------------------
extern "C" void kernel_launch(void* const* d_in, const int* in_sizes, int n_in,
                              void* d_out, int out_size, void* d_ws, size_t ws_size,
                              hipStream_t stream) {
  const int*   x       = (const int*)d_in[0];
  const float* acoord  = (const float*)d_in[1];
  const int*   atok    = (const int*)d_in[2];
  const int*   aidx    = (const int*)d_in[3];
  const int*   bidx    = (const int*)d_in[4];
  const float* emb     = (const float*)d_in[5];
  const float* coord_w = (const float*)d_in[6];
  const float* coord_b = (const float*)d_in[7];
  const float* rate1   = (const float*)d_in[8];
  const float* rate2   = (const float*)d_in[9];
  const float* ln1_g   = (const float*)d_in[10];
  const float* ln1_b   = (const float*)d_in[11];
  const float* wq      = (const float*)d_in[12];
  const float* bq      = (const float*)d_in[13];
  const float* wk      = (const float*)d_in[14];
  const float* bk      = (const float*)d_in[15];
  const float* wv      = (const float*)d_in[16];
  const float* bv      = (const float*)d_in[17];
  const float* wo      = (const float*)d_in[18];
  const float* bo      = (const float*)d_in[19];
  const float* ln2_g   = (const float*)d_in[20];
  const float* ln2_b   = (const float*)d_in[21];
  const float* w1      = (const float*)d_in[22];
  const float* b1      = (const float*)d_in[23];
  const float* w2      = (const float*)d_in[24];
  const float* b2      = (const float*)d_in[25];
  const float* lnf_g   = (const float*)d_in[26];
  const float* lnf_b   = (const float*)d_in[27];
  float* out = (float*)d_out;

  float* h = out;   // residual stream fp32, [L,B,D] row order, in d_out

  char* ws = (char*)d_ws;
  unsigned short* wqkvT = (unsigned short*)(ws);                  //  9,437,184
  unsigned short* woT   = (unsigned short*)(ws + 9437184UL);      //  3,145,728
  unsigned short* w1T   = (unsigned short*)(ws + 12582912UL);     // 12,582,912
  unsigned short* w2T   = (unsigned short*)(ws + 25165824UL);     // 12,582,912
  float*          bqkv  = (float*)(ws + 37748736UL);              //     36,864
  unsigned short* bufC  = (unsigned short*)(ws + 37785600UL);     // 67,108,864 (LN out / ctx)
  unsigned short* region= (unsigned short*)(ws + 104894464UL);    // 67,108,864 (QKV chunk / FFN mid)

  dim3 wgrid(256, NLAYER);
  wconv_kernel<<<wgrid, 256, 0, stream>>>(wq, wqkvT,           9, 512,  786432L,  262144L);
  wconv_kernel<<<wgrid, 256, 0, stream>>>(wk, wqkvT + 262144,  9, 512,  786432L,  262144L);
  wconv_kernel<<<wgrid, 256, 0, stream>>>(wv, wqkvT + 524288,  9, 512,  786432L,  262144L);
  wconv_kernel<<<wgrid, 256, 0, stream>>>(wo, woT,             9, 512,  262144L,  262144L);
  wconv_kernel<<<wgrid, 256, 0, stream>>>(w1, w1T,             9, 2048, 1048576L, 1048576L);
  wconv_kernel<<<wgrid, 256, 0, stream>>>(w2, w2T,            11, 512,  1048576L, 1048576L);
  bconcat_kernel<<<36, 256, 0, stream>>>(bq, bk, bv, bqkv);

  embed_kernel<<<BL, 128, 0, stream>>>(x, emb, rate1, h);
  scatter_kernel<<<Bb * 128, 128, 0, stream>>>(x, acoord, atok, aidx, bidx, emb,
                                               coord_w, coord_b, rate1, rate2, h);

  for (int l = 0; l < NLAYER; l++) {
    ln_kernel<0><<<16384, 256, 0, stream>>>(h, ln1_g + l * 512, ln1_b + l * 512, bufC, nullptr);
    for (int g = 0; g < NGRP; g++) {
      gemm_kernel<0, 1><<<dim3(128, 12), 256, 0, stream>>>(
          bufC, wqkvT + (long)l * 786432, bqkv + l * 1536, region, nullptr, 1536, 512, g * GB);
      attn_kernel<<<GB * Hh, 256, 0, stream>>>(region, x, bufC, g * GB);
    }
    gemm_kernel<2, 0><<<dim3(512, 4), 256, 0, stream>>>(
        bufC, woT + (long)l * 262144, bo + l * 512, nullptr, h, 512, 512, 0);
    ln_kernel<0><<<16384, 256, 0, stream>>>(h, ln2_g + l * 512, ln2_b + l * 512, bufC, nullptr);
    for (int c = 0; c < NFCH; c++) {
      gemm_kernel<1, 0><<<dim3(128, 16), 256, 0, stream>>>(
          bufC + (long)c * FCH * 512, w1T + (long)l * 1048576, b1 + l * 2048,
          region, nullptr, 2048, 512, 0);
      gemm_kernel<2, 0><<<dim3(128, 4), 256, 0, stream>>>(
          region, w2T + (long)l * 1048576, b2 + l * 512,
          nullptr, h + (long)c * FCH * 512, 512, 2048, 0);
    }
  }
  ln_kernel<1><<<16384, 256, 0, stream>>>(h, lnf_g, lnf_b, nullptr, h);
}